// Round 5
// baseline (228.091 us; speedup 1.0000x reference)
//
#include <hip/hip_runtime.h>
#include <hip/hip_bf16.h>

#define RES 300
#define NPLANE (RES * RES)   // 90000
#define NC_A 48
#define APP_DIM 27
#define KDIM 144             // 3 * NC_A
#define KS 168               // prod LDS row stride in shorts (336 B, 16B-aligned)

#define PT_TILES 352         // ceil(90000/256) p-tiles per plane
#define NPBLK (3 * PT_TILES) // 1056 plane-transpose blocks
#define LSS 268              // LDS short-stride per channel row (536 B, 8B-aligned)

// bf16 (packed in uint halves) -> f32
__device__ __forceinline__ float bf_lo(unsigned int u) { return __uint_as_float(u << 16); }
__device__ __forceinline__ float bf_hi(unsigned int u) { return __uint_as_float(u & 0xffff0000u); }

// ---------------------------------------------------------------------------
// Unified prep kernel.
//   blocks [0,1056):     plane transpose (3,64,300,300) f32 -> Tp (3,90000,64)
//     bf16 via 64ch x 256p LDS tile. Reads: 1 KB contiguous per wave-instr
//     from ONE channel row (DRAM-page friendly). Writes: dwordx4, 4 KB
//     contiguous per round. LDS 34,304 B.
//   blocks [1056,1071):  line transpose -> TlP (3,300,64) packed bf16x2 (y,y+1)
//   block  1071:         pre-pack MFMA B-fragments of basis_W (bf16, 10 KB)
// ---------------------------------------------------------------------------
__global__ __launch_bounds__(256) void prep(
    const float* __restrict__ plane, const float* __restrict__ line,
    const float* __restrict__ W,
    __hip_bfloat16* __restrict__ Tp, unsigned int* __restrict__ TlP,
    __hip_bfloat16* __restrict__ Wg) {
  __shared__ unsigned short ls[64 * LSS];   // also reused as line ltile
  const int blk = blockIdx.x;
  const int tid = threadIdx.x;

  if (blk < NPBLK) {
    const int i    = blk / PT_TILES;
    const int p0   = (blk % PT_TILES) * 256;
    const int l    = tid & 63;
    const int w    = tid >> 6;
    const int pl   = p0 + 4 * l;
    const bool pok = (pl + 3) < NPLANE;
    // read 16 rows per wave; 1 KB contiguous per instruction
    #pragma unroll
    for (int r = 0; r < 16; ++r) {
      int c = w * 16 + r;
      float4 v = make_float4(0.f, 0.f, 0.f, 0.f);
      if (pok) v = *(const float4*)&plane[(size_t)(i * 64 + c) * NPLANE + pl];
      __hip_bfloat162 h0, h1;
      h0.x = __float2bfloat16(v.x); h0.y = __float2bfloat16(v.y);
      h1.x = __float2bfloat16(v.z); h1.y = __float2bfloat16(v.w);
      uint2 u;
      u.x = *(unsigned int*)&h0;
      u.y = *(unsigned int*)&h1;
      *(uint2*)&ls[c * LSS + 4 * l] = u;   // ls[c][p] = bf16 of (c, p0+p)
    }
    __syncthreads();
    const size_t obase = ((size_t)i * NPLANE + p0) * 64;   // in bf16 units
    const int plim = min(256, NPLANE - p0);
    #pragma unroll
    for (int r = 0; r < 8; ++r) {
      int flat4 = r * 256 + tid;          // uint4 index within 32 KB out-tile
      int p  = flat4 >> 3;
      int c0 = (flat4 & 7) * 8;
      if (p < plim) {
        unsigned int x0 = (unsigned int)ls[(c0 + 0) * LSS + p] |
                          ((unsigned int)ls[(c0 + 1) * LSS + p] << 16);
        unsigned int x1 = (unsigned int)ls[(c0 + 2) * LSS + p] |
                          ((unsigned int)ls[(c0 + 3) * LSS + p] << 16);
        unsigned int x2 = (unsigned int)ls[(c0 + 4) * LSS + p] |
                          ((unsigned int)ls[(c0 + 5) * LSS + p] << 16);
        unsigned int x3 = (unsigned int)ls[(c0 + 6) * LSS + p] |
                          ((unsigned int)ls[(c0 + 7) * LSS + p] << 16);
        uint4 o = {x0, x1, x2, x3};
        *(uint4*)&Tp[obase + (size_t)p * 64 + c0] = o;
      }
    }
  } else if (blk < NPBLK + 15) {
    unsigned int* ltile = (unsigned int*)ls;
    const int b  = blk - NPBLK;
    const int i  = b / 5;
    const int y0 = (b % 5) * 64;
    const int yl = tid & 63;
    const int cq = tid >> 6;
    #pragma unroll
    for (int k = 0; k < 16; ++k) {
      int c = cq * 16 + k;
      int y = y0 + yl;
      float a = 0.f, bv = 0.f;
      if (y < RES) {
        const float* row = line + (i * 64 + c) * RES;
        a  = row[y];
        bv = row[min(y + 1, RES - 1)];
      }
      __hip_bfloat162 h;
      h.x = __float2bfloat16(a);
      h.y = __float2bfloat16(bv);
      ltile[yl * 65 + c] = *(unsigned int*)&h;
    }
    __syncthreads();
    #pragma unroll
    for (int k = 0; k < 16; ++k) {
      int ylc = k * 4 + cq;
      int c   = tid & 63;
      int y   = y0 + ylc;
      if (y < RES) TlP[((size_t)i * RES + y) * 64 + c] = ltile[ylc * 65 + c];
    }
  } else {
    // B-fragment pack: (((tile*5+kt)*64+lane)*8+j) = W[n][k], zero-padded
    for (int idx = tid; idx < 2 * 5 * 64 * 8; idx += 256) {
      int j    = idx & 7;
      int lane = (idx >> 3) & 63;
      int kt   = (idx >> 9) % 5;
      int tile = idx / (5 * 64 * 8);
      int n = tile * 16 + (lane & 15);
      int k = kt * 32 + (lane >> 4) * 8 + j;
      float v = (n < APP_DIM && k < KDIM) ? W[n * KDIM + k] : 0.f;
      Wg[idx] = __float2bfloat16(v);
    }
  }
}

// ---------------------------------------------------------------------------
// Main kernel: fused gather + blend + sigma + MFMA projection.
// 256 thr (4 waves), 64 samples/block. Channel-PAIR scheme: lane covers 2
// channels (bf16x2 dword loads); half-waves process 2 samples per iteration.
// All 15 gather loads of an iteration are issued before any blend (batched
// into register arrays) so ~15-30 loads/wave stay in flight.
// LDS = 21504 (prod) + 4608 (cw) = 26112 B -> 6 blocks/CU.
// ---------------------------------------------------------------------------
typedef __attribute__((ext_vector_type(8))) short short8;
typedef __attribute__((ext_vector_type(4))) float f32x4;

__global__ __launch_bounds__(256, 6) void tensorf_main(
    const float* __restrict__ xyz, const unsigned int* __restrict__ TpU,
    const unsigned int* __restrict__ TlP, const __hip_bfloat16* __restrict__ Wg,
    float* __restrict__ out, int n_total) {
  __shared__ __hip_bfloat16 prod[64 * KS];
  __shared__ float cw[64 * 18];

  const int tid  = threadIdx.x;
  const int lane = tid & 63;
  const int wave = tid >> 6;
  const int n0   = blockIdx.x * 64;

  // zero prod k-pad [144,168)
  for (int j = tid; j < 64 * 12; j += 256) {
    int s = j / 12, kk = (j % 12) * 2;
    *(unsigned int*)&prod[s * KS + KDIM + kk] = 0u;
  }

  // Phase 0: per-sample precompute — packed cell/line index + 4 bilinear
  // weights + line weight. 6 floats per plane per sample.
  if (tid < 64) {
    int n = min(n0 + tid, n_total - 1);
    float crd[3] = {xyz[3 * n], xyz[3 * n + 1], xyz[3 * n + 2]};
    const int m0s[3] = {0, 0, 1}, m1s[3] = {1, 2, 2}, vms[3] = {2, 1, 0};
    float* c = &cw[tid * 18];
    #pragma unroll
    for (int i = 0; i < 3; ++i) {
      float ix = fminf(fmaxf((crd[m0s[i]] + 1.f) * 149.5f, 0.f), 299.f);
      float iy = fminf(fmaxf((crd[m1s[i]] + 1.f) * 149.5f, 0.f), 299.f);
      float ly = fminf(fmaxf((crd[vms[i]] + 1.f) * 149.5f, 0.f), 299.f);
      float x0f = fminf(floorf(ix), 298.f);
      float y0f = fminf(floorf(iy), 298.f);
      float l0f = fminf(floorf(ly), 298.f);
      float wx = ix - x0f, wy = iy - y0f, lwy = ly - l0f;
      int cell = i * NPLANE + (int)y0f * RES + (int)x0f;   // < 2^19
      int lidx = i * RES + (int)l0f;                       // < 2^10
      c[i * 6 + 0] = __int_as_float(cell | (lidx << 19));
      c[i * 6 + 1] = (1.f - wx) * (1.f - wy);
      c[i * 6 + 2] = wx * (1.f - wy);
      c[i * 6 + 3] = (1.f - wx) * wy;
      c[i * 6 + 4] = wx * wy;
      c[i * 6 + 5] = lwy;
    }
  }
  __syncthreads();

  // Phase 1: gather + blend; 2 samples/wave-iteration, lane = channel pair
  const int cl   = lane & 31;
  const int half = lane >> 5;
  const int c2   = cl * 2;
  #pragma unroll 2
  for (int it = 0; it < 8; ++it) {
    int s = wave * 16 + it * 2 + half;
    const float* cp = &cw[s * 18];

    // -- batched load phase: issue all 15 VMEM ops before any use
    unsigned int u00[3], u01[3], u10[3], u11[3];
    uint2 ul[3];
    float wgt[3][5];
    #pragma unroll
    for (int i = 0; i < 3; ++i) {
      float2 q0 = *(const float2*)&cp[i * 6];       // pack, w00
      float2 q1 = *(const float2*)&cp[i * 6 + 2];   // w01, w10
      float2 q2 = *(const float2*)&cp[i * 6 + 4];   // w11, lwy
      int pk   = __float_as_int(q0.x);
      int cell = pk & 0x7FFFF;
      int lidx = pk >> 19;
      int bidx = cell * 32 + cl;                    // uint index into TpU
      u00[i] = TpU[bidx];
      u01[i] = TpU[bidx + 32];
      u10[i] = TpU[bidx + RES * 32];
      u11[i] = TpU[bidx + RES * 32 + 32];
      ul[i]  = *(const uint2*)&TlP[(lidx << 6) + c2];
      wgt[i][0] = q0.y; wgt[i][1] = q1.x; wgt[i][2] = q1.y;
      wgt[i][3] = q2.x; wgt[i][4] = q2.y;
    }

    // -- blend phase
    float dsum = 0.f;
    #pragma unroll
    for (int i = 0; i < 3; ++i) {
      float pf_l = wgt[i][0] * bf_lo(u00[i]) + wgt[i][1] * bf_lo(u01[i]) +
                   wgt[i][2] * bf_lo(u10[i]) + wgt[i][3] * bf_lo(u11[i]);
      float pf_h = wgt[i][0] * bf_hi(u00[i]) + wgt[i][1] * bf_hi(u01[i]) +
                   wgt[i][2] * bf_hi(u10[i]) + wgt[i][3] * bf_hi(u11[i]);
      float lal = bf_lo(ul[i].x), lbl = bf_hi(ul[i].x);
      float lah = bf_lo(ul[i].y), lbh = bf_hi(ul[i].y);
      float lf_l = lal + wgt[i][4] * (lbl - lal);
      float lf_h = lah + wgt[i][4] * (lbh - lah);
      float prl = pf_l * lf_l, prh = pf_h * lf_h;
      if (cl < 24) {    // app channel pairs 0..46
        __hip_bfloat162 h;
        h.x = __float2bfloat16(prl);
        h.y = __float2bfloat16(prh);
        *(unsigned int*)&prod[s * KS + i * NC_A + c2] = *(unsigned int*)&h;
      } else {          // density channel pairs 48..62
        dsum += prl + prh;
      }
    }
    // butterfly within the 8-lane density group (aligned: 24..31 / 56..63)
    dsum += __shfl_xor(dsum, 1);
    dsum += __shfl_xor(dsum, 2);
    dsum += __shfl_xor(dsum, 4);
    int n = n0 + s;
    if (cl == 24 && n < n_total) out[n] = dsum;
  }
  __syncthreads();

  // Phase 2: app = prod(64x144) @ W^T via mfma 16x16x32 bf16, B from Wg
  const int srow = lane & 15, quad = lane >> 4;
  f32x4 acc0 = {0.f, 0.f, 0.f, 0.f}, acc1 = {0.f, 0.f, 0.f, 0.f};
  const short* prodS = (const short*)prod;
  const short* WgS   = (const short*)Wg;
  const int arow = (wave * 16 + srow) * KS;
  #pragma unroll
  for (int kt = 0; kt < 5; ++kt) {
    short8 a  = *(const short8*)&prodS[arow + kt * 32 + quad * 8];
    short8 b0 = *(const short8*)&WgS[(kt * 64 + lane) * 8];
    short8 b1 = *(const short8*)&WgS[((5 + kt) * 64 + lane) * 8];
    acc0 = __builtin_amdgcn_mfma_f32_16x16x32_bf16(a, b0, acc0, 0, 0, 0);
    acc1 = __builtin_amdgcn_mfma_f32_16x16x32_bf16(a, b1, acc1, 0, 0, 0);
  }
  // C/D layout: col(d) = lane&15, row(sample) = quad*4 + reg
  float* outApp = out + n_total;
  #pragma unroll
  for (int r = 0; r < 4; ++r) {
    int n = n0 + wave * 16 + quad * 4 + r;
    if (n < n_total) {
      outApp[(size_t)n * APP_DIM + srow] = acc0[r];
      if (srow < APP_DIM - 16)
        outApp[(size_t)n * APP_DIM + 16 + srow] = acc1[r];
    }
  }
}

// ---------------------------------------------------------------------------
extern "C" void kernel_launch(void* const* d_in, const int* in_sizes, int n_in,
                              void* d_out, int out_size, void* d_ws, size_t ws_size,
                              hipStream_t stream) {
  const float* xyz   = (const float*)d_in[0];
  const float* plane = (const float*)d_in[1];
  const float* line  = (const float*)d_in[2];
  const float* W     = (const float*)d_in[3];
  float* out = (float*)d_out;
  const int N = in_sizes[0] / 3;

  char* ws = (char*)d_ws;
  __hip_bfloat16* Tp  = (__hip_bfloat16*)ws;                        // 34,560,000 B
  unsigned int*   TlP = (unsigned int*)(ws + 34560000);             //    230,400 B
  __hip_bfloat16* Wg  = (__hip_bfloat16*)(ws + 34560000 + 230400);  //     10,240 B

  prep<<<NPBLK + 16, 256, 0, stream>>>(plane, line, W, Tp, TlP, Wg);
  tensorf_main<<<(N + 63) / 64, 256, 0, stream>>>(
      xyz, (const unsigned int*)Tp, TlP, Wg, out, N);
}